// Round 1
// baseline (596.842 us; speedup 1.0000x reference)
//
#include <hip/hip_runtime.h>
#include <math.h>

#define N_PTS 16384
#define K_NBR 16
#define H_DIM 64
#define CAP   120             // per-row candidate buffer (entries)
#define NBLK  (N_PTS / 16)    // 1024 column-blocks of 16 candidates

typedef unsigned long long u64;
typedef unsigned short u16;
typedef float v2f   __attribute__((ext_vector_type(2)));
typedef float f32x4 __attribute__((ext_vector_type(4)));
typedef short bf16x8 __attribute__((ext_vector_type(8)));

// key = (order-preserving float bits, ~idx): sorts by value desc then idx asc
__device__ __forceinline__ u64 mkkey(unsigned vbits, unsigned idx) {
    unsigned of = vbits ^ (unsigned)(((int)vbits >> 31) | 0x80000000);
    return ((u64)of << 32) | (unsigned)(~idx);
}
__device__ __forceinline__ unsigned keyidx(u64 k) { return ~(unsigned)k; }

__device__ __forceinline__ float readlane_f(float v, int l) {
    return __uint_as_float(__builtin_amdgcn_readlane(__float_as_uint(v), l));
}

// bf16 RNE helpers (identical arithmetic in prep and knn A-side)
__device__ __forceinline__ u16 f2bf(float f) {
    unsigned u = __float_as_uint(f);
    return (u16)((u + 0x7FFFu + ((u >> 16) & 1u)) >> 16);
}
__device__ __forceinline__ float bf2f(u16 b) {
    return __uint_as_float(((unsigned)b) << 16);
}

// 64-lane bitonic ascending sort, float
__device__ __forceinline__ float wave_sort_f32(float v, int lane) {
#pragma unroll
    for (int k = 2; k <= 64; k <<= 1) {
#pragma unroll
        for (int j = k >> 1; j > 0; j >>= 1) {
            float o = __shfl_xor(v, j, 64);
            bool keep_min = (((lane & k) == 0) == ((lane & j) == 0));
            v = keep_min ? fminf(v, o) : fmaxf(v, o);
        }
    }
    return v;
}
// 64-lane bitonic ascending sort, u64 keys
__device__ __forceinline__ u64 wave_sort_u64(u64 v, int lane) {
#pragma unroll
    for (int k = 2; k <= 64; k <<= 1) {
#pragma unroll
        for (int j = k >> 1; j > 0; j >>= 1) {
            u64 o = __shfl_xor((unsigned long long)v, j, 64);
            bool keep_min = (((lane & k) == 0) == ((lane & j) == 0));
            u64 mn = (v < o) ? v : o;
            u64 mx = (v < o) ? o : v;
            v = keep_min ? mn : mx;
        }
    }
    return v;
}

// raise tau to 16th-largest of per-lane max VALUES, drop entries below.
// Exact invariant: tau <= 16th-largest value in buffer (>= 16 entries >= tau
// retained; boundary ties kept — they have lower index than any future cand).
struct CompRes { int nc; float tau; };
__device__ __attribute__((noinline)) CompRes wave_compact(uint2* buf, int cnt,
                                                          int lane) {
    float lm = -INFINITY;
    for (int s = lane; s < cnt; s += 64)
        lm = fmaxf(lm, __uint_as_float(buf[s].x));
    const float tv = readlane_f(wave_sort_f32(lm, lane), 48);
    int nc = 0;
    for (int s0 = 0; s0 < cnt; s0 += 64) {
        const int s = s0 + lane;
        uint2 e = make_uint2(0u, 0u);
        bool keep = false;
        if (s < cnt) { e = buf[s]; keep = (__uint_as_float(e.x) >= tv); }
        const u64 km = __ballot(keep);
        if (keep) {
            int pfx = (int)__popcll(km & ((1ull << lane) - 1));
            buf[nc + pfx] = e;   // write idx <= read idx: safe
        }
        nc += (int)__popcll(km);
    }
    CompRes r; r.nc = nc; r.tau = tv;
    return r;
}

// ---------------- prep: B-fragment array for bf16x3-split MFMA -------------
// Score(i,j) = 2*xi.xj - ||xj||^2  (row term -||xi||^2 is rank-invariant).
// K-slot map (k = c + 4p, c=0..3): pairs p:(sa,sb) = (0,0)(0,1)(1,0)(0,2)
// (2,0)(1,1)  [hh,hm,mh,hl,lh,mm of split3]; k=24..26: A=1.0, B=split3(-xx);
// k=27..31: 0.  Dropped terms (ml,lm,ll) ~2^-27 relative.
// Layout: bfrag[col][32 u16], chunk g (=k/8) at byte col*64 + g*16 so a lane
// fetches its 8 k-values with one dwordx4 load.
__global__ __launch_bounds__(256) void prep_kernel(const float4* __restrict__ x4,
                                                   u16* __restrict__ bf) {
    const int i = blockIdx.x * 256 + threadIdx.x;
    const float4 v = x4[i];
    float xx;
    {
#pragma clang fp contract(off)
        float s0 = v.x * v.x, s1 = v.y * v.y, s2 = v.z * v.z, s3 = v.w * v.w;
        xx = ((s0 + s1) + s2) + s3;
    }
    float c[4] = {v.x, v.y, v.z, v.w};
    u16 H[4], M[4], L[4];
#pragma unroll
    for (int q = 0; q < 4; ++q) {
        float f = c[q];
        u16 h = f2bf(f);            float fh = bf2f(h);
        u16 m = f2bf(f - fh);       float fm = bf2f(m);
        u16 l = f2bf(f - fh - fm);
        H[q] = h; M[q] = m; L[q] = l;
    }
    const float nx = -xx;
    u16 X0 = f2bf(nx);              float x0f = bf2f(X0);
    u16 X1 = f2bf(nx - x0f);        float x1f = bf2f(X1);
    u16 X2 = f2bf(nx - x0f - x1f);
    u16 o[32];
#pragma unroll
    for (int q = 0; q < 4; ++q) {
        o[q]      = H[q];  // p0: sb=hi
        o[4 + q]  = M[q];  // p1: sb=mid
        o[8 + q]  = H[q];  // p2: sb=hi
        o[12 + q] = L[q];  // p3: sb=lo
        o[16 + q] = H[q];  // p4: sb=hi
        o[20 + q] = M[q];  // p5: sb=mid
    }
    o[24] = X0; o[25] = X1; o[26] = X2;
    o[27] = 0; o[28] = 0; o[29] = 0; o[30] = 0; o[31] = 0;
    uint4* dst = (uint4*)(bf + (size_t)i * 32);
#pragma unroll
    for (int q2 = 0; q2 < 4; ++q2) {
        uint4 w;
        w.x = (unsigned)o[q2 * 8 + 0] | ((unsigned)o[q2 * 8 + 1] << 16);
        w.y = (unsigned)o[q2 * 8 + 2] | ((unsigned)o[q2 * 8 + 3] << 16);
        w.z = (unsigned)o[q2 * 8 + 4] | ((unsigned)o[q2 * 8 + 5] << 16);
        w.w = (unsigned)o[q2 * 8 + 6] | ((unsigned)o[q2 * 8 + 7] << 16);
        dst[q2] = w;
    }
}

// ---------------- kNN via MFMA: 16 query rows/wave, 16 cands/MFMA ----------
// Wave-private: no barriers. acc layout (m89): col=lane&15, row=(lane>>4)*4+reg.
// Per-row counters/taus live group-uniform in registers; buffers in LDS.
// Tau invariant ported 1:1 from the proven VALU kernel: stream filter strict
// '>', except the first 512 cols re-scanned with '>=' (prepass tau0 is the min
// of 16 distinct in-range candidate maxima, so all boundary-tie anchors with
// lowest indices are inserted there); compacts keep '>=' new tau.
__global__ __launch_bounds__(256, 1) void knn_kernel(
        const float4* __restrict__ x4,
        const u16* __restrict__ bfrag,
        int* __restrict__ knn) {
    __shared__ __align__(16) uint2 buf[4][16][CAP];   // 61.4 KB
    const int lane = threadIdx.x & 63;
    const int wave = threadIdx.x >> 6;
    const int g    = lane >> 4;
    const int rowbase = blockIdx.x * 64 + wave * 16;

    // ---- A fragment: row = rowbase + (lane&15), split3 of 2*x ----
    const float4 xi = x4[rowbase + (lane & 15)];
    u16 Ha[4], Ma[4], La[4];
    {
        float yy[4] = {2.f * xi.x, 2.f * xi.y, 2.f * xi.z, 2.f * xi.w};
#pragma unroll
        for (int q = 0; q < 4; ++q) {
            u16 h = f2bf(yy[q]);             float fh = bf2f(h);
            u16 m = f2bf(yy[q] - fh);        float fm = bf2f(m);
            u16 l = f2bf(yy[q] - fh - fm);
            Ha[q] = h; Ma[q] = m; La[q] = l;
        }
    }
    bf16x8 afrag;
    {
        const u16 ONEB = 0x3F80;  // bf16 1.0
#pragma unroll
        for (int q = 0; q < 4; ++q) {
            u16 lo, hi;
            if (g == 0)      { lo = Ha[q]; hi = Ha[q]; }  // p0:hi  p1:hi
            else if (g == 1) { lo = Ma[q]; hi = Ha[q]; }  // p2:mid p3:hi
            else if (g == 2) { lo = La[q]; hi = Ma[q]; }  // p4:lo  p5:mid
            else             { lo = (q < 3) ? ONEB : 0; hi = 0; }  // k24..26=1
            afrag[q]     = (short)lo;
            afrag[q + 4] = (short)hi;
        }
    }
    const f32x4 zacc = {0.f, 0.f, 0.f, 0.f};
    const bf16x8* bp = (const bf16x8*)bfrag + ((lane & 15) * 4 + g);
    const u64 gmask  = 0xFFFFull << (g * 16);
    const u64 gbelow = ((1ull << lane) - 1) & gmask;

    // ---- prepass over first 512 cols: per-lane max only, tau = group min ----
    float tau0, tau1, tau2, tau3;
    {
        float mx0 = -INFINITY, mx1 = -INFINITY, mx2 = -INFINITY, mx3 = -INFINITY;
        bf16x8 P[4];
#pragma unroll
        for (int i = 0; i < 4; ++i) P[i] = bp[i * 64];
        for (int t = 0; t < 32; t += 4) {
            bf16x8 Pn[4];
#pragma unroll
            for (int i = 0; i < 4; ++i) {
                int tp = t + 4 + i; if (tp > 31) tp = 31;
                Pn[i] = bp[tp * 64];
            }
            f32x4 aa[4];
#pragma unroll
            for (int i = 0; i < 4; ++i)
                aa[i] = __builtin_amdgcn_mfma_f32_16x16x32_bf16(afrag, P[i],
                                                                zacc, 0, 0, 0);
#pragma unroll
            for (int i = 0; i < 4; ++i) {
                mx0 = fmaxf(mx0, aa[i][0]);
                mx1 = fmaxf(mx1, aa[i][1]);
                mx2 = fmaxf(mx2, aa[i][2]);
                mx3 = fmaxf(mx3, aa[i][3]);
            }
#pragma unroll
            for (int i = 0; i < 4; ++i) P[i] = Pn[i];
        }
#pragma unroll
        for (int off = 1; off < 16; off <<= 1) {
            mx0 = fminf(mx0, __shfl_xor(mx0, off, 64));
            mx1 = fminf(mx1, __shfl_xor(mx1, off, 64));
            mx2 = fminf(mx2, __shfl_xor(mx2, off, 64));
            mx3 = fminf(mx3, __shfl_xor(mx3, off, 64));
        }
        // min of 16 distinct candidate maxima -> provably <= p16(first 512)
        tau0 = mx0; tau1 = mx1; tau2 = mx2; tau3 = mx3;
    }

    // per-row counters, group-uniform in registers (row = g*4 + j)
    unsigned c0 = 0, c1 = 0, c2 = 0, c3 = 0;

    auto insert_body = [&](f32x4 av, int colbase, bool ge) {
        const unsigned colidx = (unsigned)(colbase + (lane & 15));
        while (true) {
            const bool h0 = ge ? (av[0] >= tau0) : (av[0] > tau0);
            const bool h1 = ge ? (av[1] >= tau1) : (av[1] > tau1);
            const bool h2 = ge ? (av[2] >= tau2) : (av[2] > tau2);
            const bool h3 = ge ? (av[3] >= tau3) : (av[3] > tau3);
            const u64 m0 = __ballot(h0), m1 = __ballot(h1);
            const u64 m2 = __ballot(h2), m3 = __ballot(h3);
            const unsigned gc0 = (unsigned)__popcll(m0 & gmask);
            const unsigned gc1 = (unsigned)__popcll(m1 & gmask);
            const unsigned gc2 = (unsigned)__popcll(m2 & gmask);
            const unsigned gc3 = (unsigned)__popcll(m3 & gmask);
            const bool ov = (c0 + gc0 > CAP) || (c1 + gc1 > CAP) ||
                            (c2 + gc2 > CAP) || (c3 + gc3 > CAP);
            if (!__ballot(ov)) {
                if (m0) { const unsigned pos = c0 + (unsigned)__popcll(m0 & gbelow);
                    if (h0) buf[wave][g * 4 + 0][pos] =
                        make_uint2(__float_as_uint(av[0]), colidx); }
                if (m1) { const unsigned pos = c1 + (unsigned)__popcll(m1 & gbelow);
                    if (h1) buf[wave][g * 4 + 1][pos] =
                        make_uint2(__float_as_uint(av[1]), colidx); }
                if (m2) { const unsigned pos = c2 + (unsigned)__popcll(m2 & gbelow);
                    if (h2) buf[wave][g * 4 + 2][pos] =
                        make_uint2(__float_as_uint(av[2]), colidx); }
                if (m3) { const unsigned pos = c3 + (unsigned)__popcll(m3 & gbelow);
                    if (h3) buf[wave][g * 4 + 3][pos] =
                        make_uint2(__float_as_uint(av[3]), colidx); }
                c0 += gc0; c1 += gc1; c2 += gc2; c3 += gc3;
                return;
            }
            // rare: compact rows that might overflow, raising their taus
            for (int r = 0; r < 16; ++r) {
                const int srcl = (r >> 2) * 16;
                const int jj = r & 3;
                unsigned cr;
                if (jj == 0)      cr = __builtin_amdgcn_readlane(c0, srcl);
                else if (jj == 1) cr = __builtin_amdgcn_readlane(c1, srcl);
                else if (jj == 2) cr = __builtin_amdgcn_readlane(c2, srcl);
                else              cr = __builtin_amdgcn_readlane(c3, srcl);
                if (cr + 16u > CAP) {
                    CompRes res = wave_compact(&buf[wave][r][0], (int)cr, lane);
                    if ((lane >> 4) == (r >> 2)) {
                        if (jj == 0)      { c0 = (unsigned)res.nc; tau0 = fmaxf(tau0, res.tau); }
                        else if (jj == 1) { c1 = (unsigned)res.nc; tau1 = fmaxf(tau1, res.tau); }
                        else if (jj == 2) { c2 = (unsigned)res.nc; tau2 = fmaxf(tau2, res.tau); }
                        else              { c3 = (unsigned)res.nc; tau3 = fmaxf(tau3, res.tau); }
                    }
                }
            }
        }
    };

#define RANGE_LOOP(T0, T1, GEC)  do {                                        \
    bf16x8 Bc[8], Bn[8];                                                     \
    _Pragma("unroll")                                                        \
    for (int i = 0; i < 8; ++i) Bc[i] = bp[((T0) + i) * 64];                 \
    for (int t = (T0); t < (T1); t += 8) {                                   \
        _Pragma("unroll")                                                    \
        for (int i = 0; i < 8; ++i) {                                        \
            int tp = t + 8 + i; if (tp >= (T1)) tp = (T1) - 1;               \
            Bn[i] = bp[tp * 64];                                             \
        }                                                                    \
        f32x4 A8[8];                                                         \
        _Pragma("unroll")                                                    \
        for (int i = 0; i < 8; ++i)                                          \
            A8[i] = __builtin_amdgcn_mfma_f32_16x16x32_bf16(afrag, Bc[i],    \
                                                            zacc, 0, 0, 0);  \
        _Pragma("unroll")                                                    \
        for (int i = 0; i < 8; ++i) {                                        \
            const f32x4 av = A8[i];                                          \
            bool h0 = GEC ? (av[0] >= tau0) : (av[0] > tau0);                \
            bool h1 = GEC ? (av[1] >= tau1) : (av[1] > tau1);                \
            bool h2 = GEC ? (av[2] >= tau2) : (av[2] > tau2);                \
            bool h3 = GEC ? (av[3] >= tau3) : (av[3] > tau3);                \
            if (__ballot(h0) | __ballot(h1) | __ballot(h2) | __ballot(h3))   \
                insert_body(av, (t + i) * 16, GEC);                          \
        }                                                                    \
        _Pragma("unroll")                                                    \
        for (int i = 0; i < 8; ++i) Bc[i] = Bn[i];                           \
    }                                                                        \
} while (0)

    RANGE_LOOP(0, 32, true);       // prepass range re-scan with >= (tie anchors)
    RANGE_LOOP(32, NBLK, false);   // main stream, strict >

#undef RANGE_LOOP

    // final: per row compact (if needed), one u64-key bitonic sort, top-16
#pragma unroll 1
    for (int r = 0; r < 16; ++r) {
        const int srcl = (r >> 2) * 16;
        const int jj = r & 3;
        unsigned cru;
        if (jj == 0)      cru = __builtin_amdgcn_readlane(c0, srcl);
        else if (jj == 1) cru = __builtin_amdgcn_readlane(c1, srcl);
        else if (jj == 2) cru = __builtin_amdgcn_readlane(c2, srcl);
        else              cru = __builtin_amdgcn_readlane(c3, srcl);
        int c = (int)cru;
        uint2* br = &buf[wave][r][0];
        if (c > 64) { CompRes res = wave_compact(br, c, lane); c = res.nc; }
        u64 key = 0;                               // sentinel < any real key
        if (lane < c) { const uint2 e = br[lane]; key = mkkey(e.x, e.y); }
        key = wave_sort_u64(key, lane);
        if (lane >= 48)
            knn[(rowbase + r) * K_NBR + (lane - 48)] = (int)keyidx(key);
    }
}

// ---------------- edge-feature MLP: parallel gather + hoisted W2 -----------
// (unchanged from the proven kernel)
__global__ __launch_bounds__(256, 2) void mlp_kernel(
        const float4* __restrict__ x4,
        const int* __restrict__ knn,
        const float4* __restrict__ W2f4,
        const float* __restrict__ W1,
        const float* __restrict__ b1,
        const float* __restrict__ b2,
        float* __restrict__ out) {
    __shared__ __align__(16) float4 w2s[16][64];     // 16 KB, h4-major
    __shared__ __align__(16) float  h1s[4][32][68];  // 34 KB, per-wave
    __shared__ __align__(16) float4 xjs[4][32];      // 2 KB, per-wave gather
    const int lane = threadIdx.x & 63;
    const int wave = threadIdx.x >> 6;
    const int kq   = lane >> 4;
    const int gp   = lane & 15;
    const int p0   = (blockIdx.x * 4 + wave) * 2;    // 2 points per wave

    for (int q = threadIdx.x; q < 1024; q += 256)
        w2s[q & 15][q >> 4] = W2f4[q];               // w2s[h4][g]
    __syncthreads();

    float w1r[8];
#pragma unroll
    for (int c = 0; c < 8; ++c) w1r[c] = W1[lane * 8 + c];
    const float b1r = b1[lane];
    float b2r[4];
#pragma unroll
    for (int gq = 0; gq < 4; ++gq) b2r[gq] = b2[gq * 16 + gp];

    // parallel gather: 32 indices coalesced, 32 x4 loads in flight at once
    if (lane < 32) {
        const int pp = lane >> 4;
        const int nb = knn[(p0 + pp) * K_NBR + (lane & 15)];
        xjs[wave][lane] = x4[nb];
    }
    // wave-private LDS + in-wave vmcnt/lgkmcnt ordering: no barrier

    // layer 1 for both points (lane = hidden feature h)
#pragma unroll
    for (int pp = 0; pp < 2; ++pp) {
        const float4 xi = x4[p0 + pp];
        float hb = b1r;
        hb = fmaf(w1r[4] - w1r[0], xi.x, hb);
        hb = fmaf(w1r[5] - w1r[1], xi.y, hb);
        hb = fmaf(w1r[6] - w1r[2], xi.z, hb);
        hb = fmaf(w1r[7] - w1r[3], xi.w, hb);
#pragma unroll
        for (int k = 0; k < K_NBR; ++k) {
            const float4 xj = xjs[wave][pp * 16 + k];
            float h = hb;
            h = fmaf(w1r[0], xj.x, h);
            h = fmaf(w1r[1], xj.y, h);
            h = fmaf(w1r[2], xj.z, h);
            h = fmaf(w1r[3], xj.w, h);
            h1s[wave][pp * 16 + k][lane] = fmaxf(h, 0.0f);
        }
    }

    // layer 2: acc[pp][kk][gq] (packed pairs over h), h4-outer, w4 hoisted
    v2f acc[2][4][4];
#pragma unroll
    for (int pp = 0; pp < 2; ++pp)
#pragma unroll
        for (int kk = 0; kk < 4; ++kk)
#pragma unroll
            for (int gq = 0; gq < 4; ++gq)
                acc[pp][kk][gq] = (v2f){b2r[gq], 0.0f};

#pragma unroll
    for (int h4 = 0; h4 < 16; ++h4) {
        float4 w4[4];
#pragma unroll
        for (int gq = 0; gq < 4; ++gq) w4[gq] = w2s[h4][gq * 16 + gp];
#pragma unroll
        for (int pp = 0; pp < 2; ++pp) {
#pragma unroll
            for (int kk = 0; kk < 4; ++kk) {
                const float4 hv =
                    *(const float4*)&h1s[wave][pp * 16 + kq * 4 + kk][h4 * 4];
#pragma unroll
                for (int gq = 0; gq < 4; ++gq) {
                    acc[pp][kk][gq] = __builtin_elementwise_fma(
                        (v2f){hv.x, hv.y}, (v2f){w4[gq].x, w4[gq].y},
                        acc[pp][kk][gq]);
                    acc[pp][kk][gq] = __builtin_elementwise_fma(
                        (v2f){hv.z, hv.w}, (v2f){w4[gq].z, w4[gq].w},
                        acc[pp][kk][gq]);
                }
            }
        }
    }

#pragma unroll
    for (int pp = 0; pp < 2; ++pp) {
        float s[4];
#pragma unroll
        for (int gq = 0; gq < 4; ++gq) {
            s[gq] = 0.0f;
#pragma unroll
            for (int kk = 0; kk < 4; ++kk) {
                const float v = acc[pp][kk][gq].x + acc[pp][kk][gq].y;
                s[gq] += fmaxf(v, 0.0f);
            }
        }
#pragma unroll
        for (int off = 16; off <= 32; off <<= 1)
#pragma unroll
            for (int gq = 0; gq < 4; ++gq)
                s[gq] += __shfl_xor(s[gq], off, 64);

        out[(p0 + pp) * H_DIM + kq * 16 + gp] = s[kq] * (1.0f / 16.0f);
    }
}

extern "C" void kernel_launch(void* const* d_in, const int* in_sizes, int n_in,
                              void* d_out, int out_size, void* d_ws, size_t ws_size,
                              hipStream_t stream) {
    (void)in_sizes; (void)n_in; (void)out_size; (void)ws_size;
    const float* x  = (const float*)d_in[0];
    const float* W1 = (const float*)d_in[1];
    const float* b1 = (const float*)d_in[2];
    const float* W2 = (const float*)d_in[3];
    const float* b2 = (const float*)d_in[4];
    float* out = (float*)d_out;

    int* knn   = (int*)d_ws;                                        // 1 MB
    u16* bfrag = (u16*)((char*)d_ws + (size_t)N_PTS * K_NBR * sizeof(int)); // 1 MB

    const float4* x4 = (const float4*)x;

    prep_kernel<<<N_PTS / 256, 256, 0, stream>>>(x4, bfrag);
    knn_kernel <<<N_PTS / 64,  256, 0, stream>>>(x4, bfrag, knn);
    mlp_kernel <<<N_PTS / 8,   256, 0, stream>>>(
        x4, knn, (const float4*)W2, W1, b1, b2, out);
}

// Round 2
// 399.183 us; speedup vs baseline: 1.4952x; 1.4952x over previous
//
#include <hip/hip_runtime.h>
#include <math.h>

#define N_PTS 16384
#define K_NBR 16
#define H_DIM 64
#define CAP   64              // per-row/per-part candidate buffer (entries)
#define NBLK  (N_PTS / 16)    // 1024 column-blocks of 16 candidates
#define PBLK  (NBLK / 4)      // 256 column-blocks per wave-part

typedef unsigned long long u64;
typedef unsigned short u16;
typedef float v2f   __attribute__((ext_vector_type(2)));
typedef float f32x4 __attribute__((ext_vector_type(4)));
typedef short bf16x8 __attribute__((ext_vector_type(8)));

// key = (order-preserving float bits, ~idx): sorts by value desc then idx asc
__device__ __forceinline__ u64 mkkey(unsigned vbits, unsigned idx) {
    unsigned of = vbits ^ (unsigned)(((int)vbits >> 31) | 0x80000000);
    return ((u64)of << 32) | (unsigned)(~idx);
}
__device__ __forceinline__ unsigned keyidx(u64 k) { return ~(unsigned)k; }

__device__ __forceinline__ float readlane_f(float v, int l) {
    return __uint_as_float(__builtin_amdgcn_readlane(__float_as_uint(v), l));
}

// bf16 RNE helpers (identical arithmetic in prep and knn A-side)
__device__ __forceinline__ u16 f2bf(float f) {
    unsigned u = __float_as_uint(f);
    return (u16)((u + 0x7FFFu + ((u >> 16) & 1u)) >> 16);
}
__device__ __forceinline__ float bf2f(u16 b) {
    return __uint_as_float(((unsigned)b) << 16);
}

// 64-lane bitonic ascending sort, float
__device__ __forceinline__ float wave_sort_f32(float v, int lane) {
#pragma unroll
    for (int k = 2; k <= 64; k <<= 1) {
#pragma unroll
        for (int j = k >> 1; j > 0; j >>= 1) {
            float o = __shfl_xor(v, j, 64);
            bool keep_min = (((lane & k) == 0) == ((lane & j) == 0));
            v = keep_min ? fminf(v, o) : fmaxf(v, o);
        }
    }
    return v;
}
// 64-lane bitonic ascending sort, u64 keys
__device__ __forceinline__ u64 wave_sort_u64(u64 v, int lane) {
#pragma unroll
    for (int k = 2; k <= 64; k <<= 1) {
#pragma unroll
        for (int j = k >> 1; j > 0; j >>= 1) {
            u64 o = __shfl_xor((unsigned long long)v, j, 64);
            bool keep_min = (((lane & k) == 0) == ((lane & j) == 0));
            u64 mn = (v < o) ? v : o;
            u64 mx = (v < o) ? o : v;
            v = keep_min ? mn : mx;
        }
    }
    return v;
}

// raise tau to 16th-largest of per-lane max VALUES, drop entries below.
// Exact invariant: tau <= 16th-largest value in buffer (>= 16 entries >= tau
// retained; boundary ties kept — they have lower index than any future cand).
struct CompRes { int nc; float tau; };
__device__ __attribute__((noinline)) CompRes wave_compact(uint2* buf, int cnt,
                                                          int lane) {
    float lm = -INFINITY;
    for (int s = lane; s < cnt; s += 64)
        lm = fmaxf(lm, __uint_as_float(buf[s].x));
    const float tv = readlane_f(wave_sort_f32(lm, lane), 48);
    int nc = 0;
    for (int s0 = 0; s0 < cnt; s0 += 64) {
        const int s = s0 + lane;
        uint2 e = make_uint2(0u, 0u);
        bool keep = false;
        if (s < cnt) { e = buf[s]; keep = (__uint_as_float(e.x) >= tv); }
        const u64 km = __ballot(keep);
        if (keep) {
            int pfx = (int)__popcll(km & ((1ull << lane) - 1));
            buf[nc + pfx] = e;   // write idx <= read idx: safe
        }
        nc += (int)__popcll(km);
    }
    CompRes r; r.nc = nc; r.tau = tv;
    return r;
}

// ---------------- prep: B-fragment array for bf16x3-split MFMA -------------
// Score(i,j) = 2*xi.xj - ||xj||^2  (row term -||xi||^2 is rank-invariant).
// K-slot map (k = c + 4p, c=0..3): pairs p:(sa,sb) = (0,0)(0,1)(1,0)(0,2)
// (2,0)(1,1)  [hh,hm,mh,hl,lh,mm of split3]; k=24..26: A=1.0, B=split3(-xx);
// k=27..31: 0.  Dropped terms (ml,lm,ll) ~2^-27 relative.
// Layout: bfrag[col][32 u16], chunk g (=k/8) at byte col*64 + g*16 so a lane
// fetches its 8 k-values with one dwordx4 load.
__global__ __launch_bounds__(256) void prep_kernel(const float4* __restrict__ x4,
                                                   u16* __restrict__ bf) {
    const int i = blockIdx.x * 256 + threadIdx.x;
    const float4 v = x4[i];
    float xx;
    {
#pragma clang fp contract(off)
        float s0 = v.x * v.x, s1 = v.y * v.y, s2 = v.z * v.z, s3 = v.w * v.w;
        xx = ((s0 + s1) + s2) + s3;
    }
    float c[4] = {v.x, v.y, v.z, v.w};
    u16 H[4], M[4], L[4];
#pragma unroll
    for (int q = 0; q < 4; ++q) {
        float f = c[q];
        u16 h = f2bf(f);            float fh = bf2f(h);
        u16 m = f2bf(f - fh);       float fm = bf2f(m);
        u16 l = f2bf(f - fh - fm);
        H[q] = h; M[q] = m; L[q] = l;
    }
    const float nx = -xx;
    u16 X0 = f2bf(nx);              float x0f = bf2f(X0);
    u16 X1 = f2bf(nx - x0f);        float x1f = bf2f(X1);
    u16 X2 = f2bf(nx - x0f - x1f);
    u16 o[32];
#pragma unroll
    for (int q = 0; q < 4; ++q) {
        o[q]      = H[q];  // p0: sb=hi
        o[4 + q]  = M[q];  // p1: sb=mid
        o[8 + q]  = H[q];  // p2: sb=hi
        o[12 + q] = L[q];  // p3: sb=lo
        o[16 + q] = H[q];  // p4: sb=hi
        o[20 + q] = M[q];  // p5: sb=mid
    }
    o[24] = X0; o[25] = X1; o[26] = X2;
    o[27] = 0; o[28] = 0; o[29] = 0; o[30] = 0; o[31] = 0;
    uint4* dst = (uint4*)(bf + (size_t)i * 32);
#pragma unroll
    for (int q2 = 0; q2 < 4; ++q2) {
        uint4 w;
        w.x = (unsigned)o[q2 * 8 + 0] | ((unsigned)o[q2 * 8 + 1] << 16);
        w.y = (unsigned)o[q2 * 8 + 2] | ((unsigned)o[q2 * 8 + 3] << 16);
        w.z = (unsigned)o[q2 * 8 + 4] | ((unsigned)o[q2 * 8 + 5] << 16);
        w.w = (unsigned)o[q2 * 8 + 6] | ((unsigned)o[q2 * 8 + 7] << 16);
        dst[q2] = w;
    }
}

// ---------------- kNN via MFMA: column-split across 4 waves ----------------
// Block = 4 waves, SAME 16 rows, wave w scans columns [w*4096,(w+1)*4096).
// Grid N/16 = 1024 blocks -> 4096 waves (R1 post-mortem: the 1024-wave
// variant ran at 1 wave/SIMD, fully latency-exposed). Per-part tau/compact
// invariants are part-local and unchanged; each part emits an exact top-16
// (u64 keys, value desc / idx asc) into its buffer slots 0..15; in-block
// merge sorts the 4x16 union per row. acc layout (m89): col=lane&15,
// row=(lane>>4)*4+reg. LDS 32 KB -> 4 blk/CU = 16 waves/CU.
__global__ __launch_bounds__(256, 4) void knn_kernel(
        const float4* __restrict__ x4,
        const u16* __restrict__ bfrag,
        int* __restrict__ knn) {
    __shared__ __align__(16) uint2 buf[4][16][CAP];   // 32 KB
    const int lane = threadIdx.x & 63;
    const int wave = threadIdx.x >> 6;
    const int g    = lane >> 4;
    const int rowbase = blockIdx.x * 16;
    const int pblk = wave * PBLK;          // part's first 16-col block

    // ---- A fragment: row = rowbase + (lane&15), split3 of 2*x ----
    const float4 xi = x4[rowbase + (lane & 15)];
    u16 Ha[4], Ma[4], La[4];
    {
        float yy[4] = {2.f * xi.x, 2.f * xi.y, 2.f * xi.z, 2.f * xi.w};
#pragma unroll
        for (int q = 0; q < 4; ++q) {
            u16 h = f2bf(yy[q]);             float fh = bf2f(h);
            u16 m = f2bf(yy[q] - fh);        float fm = bf2f(m);
            u16 l = f2bf(yy[q] - fh - fm);
            Ha[q] = h; Ma[q] = m; La[q] = l;
        }
    }
    bf16x8 afrag;
    {
        const u16 ONEB = 0x3F80;  // bf16 1.0
#pragma unroll
        for (int q = 0; q < 4; ++q) {
            u16 lo, hi;
            if (g == 0)      { lo = Ha[q]; hi = Ha[q]; }  // p0:hi  p1:hi
            else if (g == 1) { lo = Ma[q]; hi = Ha[q]; }  // p2:mid p3:hi
            else if (g == 2) { lo = La[q]; hi = Ma[q]; }  // p4:lo  p5:mid
            else             { lo = (q < 3) ? ONEB : 0; hi = 0; }  // k24..26=1
            afrag[q]     = (short)lo;
            afrag[q + 4] = (short)hi;
        }
    }
    const f32x4 zacc = {0.f, 0.f, 0.f, 0.f};
    const bf16x8* bp = (const bf16x8*)bfrag + (size_t)pblk * 64 +
                       ((lane & 15) * 4 + g);
    const u64 gmask  = 0xFFFFull << (g * 16);
    const u64 gbelow = ((1ull << lane) - 1) & gmask;

    // ---- prepass over part's first 512 cols: tau = group-min of lane maxima
    float tau0, tau1, tau2, tau3;
    {
        float mx0 = -INFINITY, mx1 = -INFINITY, mx2 = -INFINITY, mx3 = -INFINITY;
        bf16x8 P[4];
#pragma unroll
        for (int i = 0; i < 4; ++i) P[i] = bp[i * 64];
        for (int t = 0; t < 32; t += 4) {
            bf16x8 Pn[4];
#pragma unroll
            for (int i = 0; i < 4; ++i) {
                int tp = t + 4 + i; if (tp > 31) tp = 31;
                Pn[i] = bp[tp * 64];
            }
            f32x4 aa[4];
#pragma unroll
            for (int i = 0; i < 4; ++i)
                aa[i] = __builtin_amdgcn_mfma_f32_16x16x32_bf16(afrag, P[i],
                                                                zacc, 0, 0, 0);
#pragma unroll
            for (int i = 0; i < 4; ++i) {
                mx0 = fmaxf(mx0, aa[i][0]);
                mx1 = fmaxf(mx1, aa[i][1]);
                mx2 = fmaxf(mx2, aa[i][2]);
                mx3 = fmaxf(mx3, aa[i][3]);
            }
#pragma unroll
            for (int i = 0; i < 4; ++i) P[i] = Pn[i];
        }
#pragma unroll
        for (int off = 1; off < 16; off <<= 1) {
            mx0 = fminf(mx0, __shfl_xor(mx0, off, 64));
            mx1 = fminf(mx1, __shfl_xor(mx1, off, 64));
            mx2 = fminf(mx2, __shfl_xor(mx2, off, 64));
            mx3 = fminf(mx3, __shfl_xor(mx3, off, 64));
        }
        // min of 16 distinct part-local candidate maxima -> <= part's p16
        tau0 = mx0; tau1 = mx1; tau2 = mx2; tau3 = mx3;
    }

    // per-row counters, group-uniform in registers (row = g*4 + j)
    unsigned c0 = 0, c1 = 0, c2 = 0, c3 = 0;

    auto insert_body = [&](f32x4 av, int colbase, bool ge) {
        const unsigned colidx = (unsigned)(colbase + (lane & 15));
        while (true) {
            const bool h0 = ge ? (av[0] >= tau0) : (av[0] > tau0);
            const bool h1 = ge ? (av[1] >= tau1) : (av[1] > tau1);
            const bool h2 = ge ? (av[2] >= tau2) : (av[2] > tau2);
            const bool h3 = ge ? (av[3] >= tau3) : (av[3] > tau3);
            const u64 m0 = __ballot(h0), m1 = __ballot(h1);
            const u64 m2 = __ballot(h2), m3 = __ballot(h3);
            const unsigned gc0 = (unsigned)__popcll(m0 & gmask);
            const unsigned gc1 = (unsigned)__popcll(m1 & gmask);
            const unsigned gc2 = (unsigned)__popcll(m2 & gmask);
            const unsigned gc3 = (unsigned)__popcll(m3 & gmask);
            const bool ov = (c0 + gc0 > CAP) || (c1 + gc1 > CAP) ||
                            (c2 + gc2 > CAP) || (c3 + gc3 > CAP);
            if (!__ballot(ov)) {
                if (m0) { const unsigned pos = c0 + (unsigned)__popcll(m0 & gbelow);
                    if (h0) buf[wave][g * 4 + 0][pos] =
                        make_uint2(__float_as_uint(av[0]), colidx); }
                if (m1) { const unsigned pos = c1 + (unsigned)__popcll(m1 & gbelow);
                    if (h1) buf[wave][g * 4 + 1][pos] =
                        make_uint2(__float_as_uint(av[1]), colidx); }
                if (m2) { const unsigned pos = c2 + (unsigned)__popcll(m2 & gbelow);
                    if (h2) buf[wave][g * 4 + 2][pos] =
                        make_uint2(__float_as_uint(av[2]), colidx); }
                if (m3) { const unsigned pos = c3 + (unsigned)__popcll(m3 & gbelow);
                    if (h3) buf[wave][g * 4 + 3][pos] =
                        make_uint2(__float_as_uint(av[3]), colidx); }
                c0 += gc0; c1 += gc1; c2 += gc2; c3 += gc3;
                return;
            }
            // rare: compact rows that might overflow, raising their taus
            for (int r = 0; r < 16; ++r) {
                const int srcl = (r >> 2) * 16;
                const int jj = r & 3;
                unsigned cr;
                if (jj == 0)      cr = __builtin_amdgcn_readlane(c0, srcl);
                else if (jj == 1) cr = __builtin_amdgcn_readlane(c1, srcl);
                else if (jj == 2) cr = __builtin_amdgcn_readlane(c2, srcl);
                else              cr = __builtin_amdgcn_readlane(c3, srcl);
                if (cr + 16u > CAP) {
                    CompRes res = wave_compact(&buf[wave][r][0], (int)cr, lane);
                    if ((lane >> 4) == (r >> 2)) {
                        if (jj == 0)      { c0 = (unsigned)res.nc; tau0 = fmaxf(tau0, res.tau); }
                        else if (jj == 1) { c1 = (unsigned)res.nc; tau1 = fmaxf(tau1, res.tau); }
                        else if (jj == 2) { c2 = (unsigned)res.nc; tau2 = fmaxf(tau2, res.tau); }
                        else              { c3 = (unsigned)res.nc; tau3 = fmaxf(tau3, res.tau); }
                    }
                }
            }
        }
    };

#define RANGE_LOOP(T0, T1, GEC)  do {                                        \
    bf16x8 Bc[8], Bn[8];                                                     \
    _Pragma("unroll")                                                        \
    for (int i = 0; i < 8; ++i) Bc[i] = bp[((T0) + i) * 64];                 \
    for (int t = (T0); t < (T1); t += 8) {                                   \
        _Pragma("unroll")                                                    \
        for (int i = 0; i < 8; ++i) {                                        \
            int tp = t + 8 + i; if (tp >= (T1)) tp = (T1) - 1;               \
            Bn[i] = bp[tp * 64];                                             \
        }                                                                    \
        f32x4 A8[8];                                                         \
        _Pragma("unroll")                                                    \
        for (int i = 0; i < 8; ++i)                                          \
            A8[i] = __builtin_amdgcn_mfma_f32_16x16x32_bf16(afrag, Bc[i],    \
                                                            zacc, 0, 0, 0);  \
        _Pragma("unroll")                                                    \
        for (int i = 0; i < 8; ++i) {                                        \
            const f32x4 av = A8[i];                                          \
            bool h0 = GEC ? (av[0] >= tau0) : (av[0] > tau0);                \
            bool h1 = GEC ? (av[1] >= tau1) : (av[1] > tau1);                \
            bool h2 = GEC ? (av[2] >= tau2) : (av[2] > tau2);                \
            bool h3 = GEC ? (av[3] >= tau3) : (av[3] > tau3);                \
            if (__ballot(h0 | h1 | h2 | h3))                                 \
                insert_body(av, (pblk + t + i) * 16, GEC);                   \
        }                                                                    \
        _Pragma("unroll")                                                    \
        for (int i = 0; i < 8; ++i) Bc[i] = Bn[i];                           \
    }                                                                        \
} while (0)

    RANGE_LOOP(0, 32, true);       // prepass range re-scan with >= (tie anchors)
    RANGE_LOOP(32, PBLK, false);   // main stream, strict >

#undef RANGE_LOOP

    // ---- per-part finalize: compact guard, sort, park top-16 keys in slots
#pragma unroll 1
    for (int r = 0; r < 16; ++r) {
        const int srcl = (r >> 2) * 16;
        const int jj = r & 3;
        unsigned cru;
        if (jj == 0)      cru = __builtin_amdgcn_readlane(c0, srcl);
        else if (jj == 1) cru = __builtin_amdgcn_readlane(c1, srcl);
        else if (jj == 2) cru = __builtin_amdgcn_readlane(c2, srcl);
        else              cru = __builtin_amdgcn_readlane(c3, srcl);
        int c = (int)cru;
        uint2* br = &buf[wave][r][0];
        if (c > 64) { CompRes res = wave_compact(br, c, lane); c = res.nc; }
        u64 key = 0;                               // sentinel < any real key
        if (lane < c) { const uint2 e = br[lane]; key = mkkey(e.x, e.y); }
        key = wave_sort_u64(key, lane);
        if (lane >= 48)
            *(u64*)&buf[wave][r][lane - 48] = key;  // part top-16, slots 0..15
    }

    // ---- in-block merge: 64 keys per row (4 disjoint parts x 16) ----
    __syncthreads();
#pragma unroll
    for (int rr = 0; rr < 4; ++rr) {
        const int r2 = wave * 4 + rr;
        u64 key = *(const u64*)&buf[lane >> 4][r2][lane & 15];
        key = wave_sort_u64(key, lane);
        if (lane >= 48)
            knn[(rowbase + r2) * K_NBR + (lane - 48)] = (int)keyidx(key);
    }
}

// ---------------- edge-feature MLP: parallel gather + hoisted W2 -----------
// (unchanged from the proven kernel)
__global__ __launch_bounds__(256, 2) void mlp_kernel(
        const float4* __restrict__ x4,
        const int* __restrict__ knn,
        const float4* __restrict__ W2f4,
        const float* __restrict__ W1,
        const float* __restrict__ b1,
        const float* __restrict__ b2,
        float* __restrict__ out) {
    __shared__ __align__(16) float4 w2s[16][64];     // 16 KB, h4-major
    __shared__ __align__(16) float  h1s[4][32][68];  // 34 KB, per-wave
    __shared__ __align__(16) float4 xjs[4][32];      // 2 KB, per-wave gather
    const int lane = threadIdx.x & 63;
    const int wave = threadIdx.x >> 6;
    const int kq   = lane >> 4;
    const int gp   = lane & 15;
    const int p0   = (blockIdx.x * 4 + wave) * 2;    // 2 points per wave

    for (int q = threadIdx.x; q < 1024; q += 256)
        w2s[q & 15][q >> 4] = W2f4[q];               // w2s[h4][g]
    __syncthreads();

    float w1r[8];
#pragma unroll
    for (int c = 0; c < 8; ++c) w1r[c] = W1[lane * 8 + c];
    const float b1r = b1[lane];
    float b2r[4];
#pragma unroll
    for (int gq = 0; gq < 4; ++gq) b2r[gq] = b2[gq * 16 + gp];

    // parallel gather: 32 indices coalesced, 32 x4 loads in flight at once
    if (lane < 32) {
        const int pp = lane >> 4;
        const int nb = knn[(p0 + pp) * K_NBR + (lane & 15)];
        xjs[wave][lane] = x4[nb];
    }
    // wave-private LDS + in-wave vmcnt/lgkmcnt ordering: no barrier

    // layer 1 for both points (lane = hidden feature h)
#pragma unroll
    for (int pp = 0; pp < 2; ++pp) {
        const float4 xi = x4[p0 + pp];
        float hb = b1r;
        hb = fmaf(w1r[4] - w1r[0], xi.x, hb);
        hb = fmaf(w1r[5] - w1r[1], xi.y, hb);
        hb = fmaf(w1r[6] - w1r[2], xi.z, hb);
        hb = fmaf(w1r[7] - w1r[3], xi.w, hb);
#pragma unroll
        for (int k = 0; k < K_NBR; ++k) {
            const float4 xj = xjs[wave][pp * 16 + k];
            float h = hb;
            h = fmaf(w1r[0], xj.x, h);
            h = fmaf(w1r[1], xj.y, h);
            h = fmaf(w1r[2], xj.z, h);
            h = fmaf(w1r[3], xj.w, h);
            h1s[wave][pp * 16 + k][lane] = fmaxf(h, 0.0f);
        }
    }

    // layer 2: acc[pp][kk][gq] (packed pairs over h), h4-outer, w4 hoisted
    v2f acc[2][4][4];
#pragma unroll
    for (int pp = 0; pp < 2; ++pp)
#pragma unroll
        for (int kk = 0; kk < 4; ++kk)
#pragma unroll
            for (int gq = 0; gq < 4; ++gq)
                acc[pp][kk][gq] = (v2f){b2r[gq], 0.0f};

#pragma unroll
    for (int h4 = 0; h4 < 16; ++h4) {
        float4 w4[4];
#pragma unroll
        for (int gq = 0; gq < 4; ++gq) w4[gq] = w2s[h4][gq * 16 + gp];
#pragma unroll
        for (int pp = 0; pp < 2; ++pp) {
#pragma unroll
            for (int kk = 0; kk < 4; ++kk) {
                const float4 hv =
                    *(const float4*)&h1s[wave][pp * 16 + kq * 4 + kk][h4 * 4];
#pragma unroll
                for (int gq = 0; gq < 4; ++gq) {
                    acc[pp][kk][gq] = __builtin_elementwise_fma(
                        (v2f){hv.x, hv.y}, (v2f){w4[gq].x, w4[gq].y},
                        acc[pp][kk][gq]);
                    acc[pp][kk][gq] = __builtin_elementwise_fma(
                        (v2f){hv.z, hv.w}, (v2f){w4[gq].z, w4[gq].w},
                        acc[pp][kk][gq]);
                }
            }
        }
    }

#pragma unroll
    for (int pp = 0; pp < 2; ++pp) {
        float s[4];
#pragma unroll
        for (int gq = 0; gq < 4; ++gq) {
            s[gq] = 0.0f;
#pragma unroll
            for (int kk = 0; kk < 4; ++kk) {
                const float v = acc[pp][kk][gq].x + acc[pp][kk][gq].y;
                s[gq] += fmaxf(v, 0.0f);
            }
        }
#pragma unroll
        for (int off = 16; off <= 32; off <<= 1)
#pragma unroll
            for (int gq = 0; gq < 4; ++gq)
                s[gq] += __shfl_xor(s[gq], off, 64);

        out[(p0 + pp) * H_DIM + kq * 16 + gp] = s[kq] * (1.0f / 16.0f);
    }
}

extern "C" void kernel_launch(void* const* d_in, const int* in_sizes, int n_in,
                              void* d_out, int out_size, void* d_ws, size_t ws_size,
                              hipStream_t stream) {
    (void)in_sizes; (void)n_in; (void)out_size; (void)ws_size;
    const float* x  = (const float*)d_in[0];
    const float* W1 = (const float*)d_in[1];
    const float* b1 = (const float*)d_in[2];
    const float* W2 = (const float*)d_in[3];
    const float* b2 = (const float*)d_in[4];
    float* out = (float*)d_out;

    int* knn   = (int*)d_ws;                                        // 1 MB
    u16* bfrag = (u16*)((char*)d_ws + (size_t)N_PTS * K_NBR * sizeof(int)); // 1 MB

    const float4* x4 = (const float4*)x;

    prep_kernel<<<N_PTS / 256, 256, 0, stream>>>(x4, bfrag);
    knn_kernel <<<N_PTS / 16,  256, 0, stream>>>(x4, bfrag, knn);
    mlp_kernel <<<N_PTS / 8,   256, 0, stream>>>(
        x4, knn, (const float4*)W2, W1, b1, b2, out);
}

// Round 3
// 361.203 us; speedup vs baseline: 1.6524x; 1.1051x over previous
//
#include <hip/hip_runtime.h>
#include <math.h>

#define N_PTS 16384
#define K_NBR 16
#define H_DIM 64
#define CAP   80              // per-row/per-part candidate buffer (entries)
#define NBLK  (N_PTS / 16)    // 1024 column-blocks of 16 candidates
#define PBLK  (NBLK / 4)      // 256 column-blocks per wave-part

typedef unsigned long long u64;
typedef unsigned short u16;
typedef float v2f   __attribute__((ext_vector_type(2)));
typedef float f32x4 __attribute__((ext_vector_type(4)));
typedef short bf16x8 __attribute__((ext_vector_type(8)));

// key = (order-preserving float bits, ~idx): sorts by value desc then idx asc
__device__ __forceinline__ u64 mkkey(unsigned vbits, unsigned idx) {
    unsigned of = vbits ^ (unsigned)(((int)vbits >> 31) | 0x80000000);
    return ((u64)of << 32) | (unsigned)(~idx);
}
__device__ __forceinline__ unsigned keyidx(u64 k) { return ~(unsigned)k; }

__device__ __forceinline__ float readlane_f(float v, int l) {
    return __uint_as_float(__builtin_amdgcn_readlane(__float_as_uint(v), l));
}

// bf16 RNE helpers (identical arithmetic in prep and knn A-side)
__device__ __forceinline__ u16 f2bf(float f) {
    unsigned u = __float_as_uint(f);
    return (u16)((u + 0x7FFFu + ((u >> 16) & 1u)) >> 16);
}
__device__ __forceinline__ float bf2f(u16 b) {
    return __uint_as_float(((unsigned)b) << 16);
}

// 64-lane bitonic ascending sort, float
__device__ __forceinline__ float wave_sort_f32(float v, int lane) {
#pragma unroll
    for (int k = 2; k <= 64; k <<= 1) {
#pragma unroll
        for (int j = k >> 1; j > 0; j >>= 1) {
            float o = __shfl_xor(v, j, 64);
            bool keep_min = (((lane & k) == 0) == ((lane & j) == 0));
            v = keep_min ? fminf(v, o) : fmaxf(v, o);
        }
    }
    return v;
}
// 64-lane bitonic ascending sort, u64 keys
__device__ __forceinline__ u64 wave_sort_u64(u64 v, int lane) {
#pragma unroll
    for (int k = 2; k <= 64; k <<= 1) {
#pragma unroll
        for (int j = k >> 1; j > 0; j >>= 1) {
            u64 o = __shfl_xor((unsigned long long)v, j, 64);
            bool keep_min = (((lane & k) == 0) == ((lane & j) == 0));
            u64 mn = (v < o) ? v : o;
            u64 mx = (v < o) ? o : v;
            v = keep_min ? mn : mx;
        }
    }
    return v;
}

// raise tau to 16th-largest of per-lane max VALUES, drop entries below.
// Exact invariant: tau <= 16th-largest value in buffer (>= 16 entries >= tau
// retained; boundary ties kept — they have lower index than any future cand).
struct CompRes { int nc; float tau; };
__device__ __attribute__((noinline)) CompRes wave_compact(uint2* buf, int cnt,
                                                          int lane) {
    float lm = -INFINITY;
    for (int s = lane; s < cnt; s += 64)
        lm = fmaxf(lm, __uint_as_float(buf[s].x));
    const float tv = readlane_f(wave_sort_f32(lm, lane), 48);
    int nc = 0;
    for (int s0 = 0; s0 < cnt; s0 += 64) {
        const int s = s0 + lane;
        uint2 e = make_uint2(0u, 0u);
        bool keep = false;
        if (s < cnt) { e = buf[s]; keep = (__uint_as_float(e.x) >= tv); }
        const u64 km = __ballot(keep);
        if (keep) {
            int pfx = (int)__popcll(km & ((1ull << lane) - 1));
            buf[nc + pfx] = e;   // write idx <= read idx: safe
        }
        nc += (int)__popcll(km);
    }
    CompRes r; r.nc = nc; r.tau = tv;
    return r;
}

// ---------------- prep: B-fragment array for bf16x3-split MFMA -------------
// Score(i,j) = 2*xi.xj - ||xj||^2  (row term -||xi||^2 is rank-invariant).
// K-slot map (k = c + 4p, c=0..3): pairs p:(sa,sb) = (0,0)(0,1)(1,0)(0,2)
// (2,0)(1,1)  [hh,hm,mh,hl,lh,mm of split3]; k=24..26: A=1.0, B=split3(-xx);
// k=27..31: 0.  Dropped terms (ml,lm,ll) ~2^-27 relative.
// Layout: bfrag[col][32 u16], chunk g (=k/8) at byte col*64 + g*16 so a lane
// fetches its 8 k-values with one dwordx4 load.
__global__ __launch_bounds__(256) void prep_kernel(const float4* __restrict__ x4,
                                                   u16* __restrict__ bf) {
    const int i = blockIdx.x * 256 + threadIdx.x;
    const float4 v = x4[i];
    float xx;
    {
#pragma clang fp contract(off)
        float s0 = v.x * v.x, s1 = v.y * v.y, s2 = v.z * v.z, s3 = v.w * v.w;
        xx = ((s0 + s1) + s2) + s3;
    }
    float c[4] = {v.x, v.y, v.z, v.w};
    u16 H[4], M[4], L[4];
#pragma unroll
    for (int q = 0; q < 4; ++q) {
        float f = c[q];
        u16 h = f2bf(f);            float fh = bf2f(h);
        u16 m = f2bf(f - fh);       float fm = bf2f(m);
        u16 l = f2bf(f - fh - fm);
        H[q] = h; M[q] = m; L[q] = l;
    }
    const float nx = -xx;
    u16 X0 = f2bf(nx);              float x0f = bf2f(X0);
    u16 X1 = f2bf(nx - x0f);        float x1f = bf2f(X1);
    u16 X2 = f2bf(nx - x0f - x1f);
    u16 o[32];
#pragma unroll
    for (int q = 0; q < 4; ++q) {
        o[q]      = H[q];  // p0: sb=hi
        o[4 + q]  = M[q];  // p1: sb=mid
        o[8 + q]  = H[q];  // p2: sb=hi
        o[12 + q] = L[q];  // p3: sb=lo
        o[16 + q] = H[q];  // p4: sb=hi
        o[20 + q] = M[q];  // p5: sb=mid
    }
    o[24] = X0; o[25] = X1; o[26] = X2;
    o[27] = 0; o[28] = 0; o[29] = 0; o[30] = 0; o[31] = 0;
    uint4* dst = (uint4*)(bf + (size_t)i * 32);
#pragma unroll
    for (int q2 = 0; q2 < 4; ++q2) {
        uint4 w;
        w.x = (unsigned)o[q2 * 8 + 0] | ((unsigned)o[q2 * 8 + 1] << 16);
        w.y = (unsigned)o[q2 * 8 + 2] | ((unsigned)o[q2 * 8 + 3] << 16);
        w.z = (unsigned)o[q2 * 8 + 4] | ((unsigned)o[q2 * 8 + 5] << 16);
        w.w = (unsigned)o[q2 * 8 + 6] | ((unsigned)o[q2 * 8 + 7] << 16);
        dst[q2] = w;
    }
}

// ---------------- kNN via MFMA: column-split across 4 waves ----------------
// Block = 4 waves, SAME 16 rows, wave w scans columns [w*4096,(w+1)*4096).
// R2 post-mortem: depth-8 B-prefetch (64 VGPR) + outlined insert lambda
// spilled to scratch (VGPR=64, WRITE_SIZE 15MB). This version: depth-4
// prefetch, macro-inlined lean insert (ballot-direct masks, umax overflow
// check, bit-test writes), CAP=80/LDS=40KB pinning 4 blk/CU = 16 waves/CU.
__global__ __launch_bounds__(256, 4) void knn_kernel(
        const float4* __restrict__ x4,
        const u16* __restrict__ bfrag,
        int* __restrict__ knn) {
    __shared__ __align__(16) uint2 buf[4][16][CAP];   // 40 KB
    const int lane = threadIdx.x & 63;
    const int wave = threadIdx.x >> 6;
    const int g    = lane >> 4;
    const int rowbase = blockIdx.x * 16;
    const int pblk = wave * PBLK;          // part's first 16-col block

    // ---- A fragment: row = rowbase + (lane&15), split3 of 2*x ----
    const float4 xi = x4[rowbase + (lane & 15)];
    u16 Ha[4], Ma[4], La[4];
    {
        float yy[4] = {2.f * xi.x, 2.f * xi.y, 2.f * xi.z, 2.f * xi.w};
#pragma unroll
        for (int q = 0; q < 4; ++q) {
            u16 h = f2bf(yy[q]);             float fh = bf2f(h);
            u16 m = f2bf(yy[q] - fh);        float fm = bf2f(m);
            u16 l = f2bf(yy[q] - fh - fm);
            Ha[q] = h; Ma[q] = m; La[q] = l;
        }
    }
    bf16x8 afrag;
    {
        const u16 ONEB = 0x3F80;  // bf16 1.0
#pragma unroll
        for (int q = 0; q < 4; ++q) {
            u16 lo, hi;
            if (g == 0)      { lo = Ha[q]; hi = Ha[q]; }  // p0:hi  p1:hi
            else if (g == 1) { lo = Ma[q]; hi = Ha[q]; }  // p2:mid p3:hi
            else if (g == 2) { lo = La[q]; hi = Ma[q]; }  // p4:lo  p5:mid
            else             { lo = (q < 3) ? ONEB : 0; hi = 0; }  // k24..26=1
            afrag[q]     = (short)lo;
            afrag[q + 4] = (short)hi;
        }
    }
    const f32x4 zacc = {0.f, 0.f, 0.f, 0.f};
    const bf16x8* bp = (const bf16x8*)bfrag + (size_t)pblk * 64 +
                       ((lane & 15) * 4 + g);
    const u64 gmask  = 0xFFFFull << (g * 16);
    const u64 gbelow = ((1ull << lane) - 1) & gmask;

    // ---- prepass over part's first 512 cols: tau = group-min of lane maxima
    float tau0, tau1, tau2, tau3;
    {
        float mx0 = -INFINITY, mx1 = -INFINITY, mx2 = -INFINITY, mx3 = -INFINITY;
        bf16x8 P[4];
#pragma unroll
        for (int i = 0; i < 4; ++i) P[i] = bp[i * 64];
        for (int t = 0; t < 32; t += 4) {
            bf16x8 Pn[4];
#pragma unroll
            for (int i = 0; i < 4; ++i) {
                int tp = t + 4 + i; if (tp > 31) tp = 31;
                Pn[i] = bp[tp * 64];
            }
            f32x4 aa[4];
#pragma unroll
            for (int i = 0; i < 4; ++i)
                aa[i] = __builtin_amdgcn_mfma_f32_16x16x32_bf16(afrag, P[i],
                                                                zacc, 0, 0, 0);
#pragma unroll
            for (int i = 0; i < 4; ++i) {
                mx0 = fmaxf(mx0, aa[i][0]);
                mx1 = fmaxf(mx1, aa[i][1]);
                mx2 = fmaxf(mx2, aa[i][2]);
                mx3 = fmaxf(mx3, aa[i][3]);
            }
#pragma unroll
            for (int i = 0; i < 4; ++i) P[i] = Pn[i];
        }
#pragma unroll
        for (int off = 1; off < 16; off <<= 1) {
            mx0 = fminf(mx0, __shfl_xor(mx0, off, 64));
            mx1 = fminf(mx1, __shfl_xor(mx1, off, 64));
            mx2 = fminf(mx2, __shfl_xor(mx2, off, 64));
            mx3 = fminf(mx3, __shfl_xor(mx3, off, 64));
        }
        // min of 16 distinct part-local candidate maxima -> <= part's p16
        tau0 = mx0; tau1 = mx1; tau2 = mx2; tau3 = mx3;
    }

    // per-row counters, group-uniform in registers (row = g*4 + j)
    unsigned c0 = 0, c1 = 0, c2 = 0, c3 = 0;

// lean insert: masks come from the filter ballots; gc via 64-bit popc;
// overflow pre-check via umax chain; writes bit-test the ORIGINAL mask
// (tau may have been raised by a compact — counts must match writes).
#define INSERT_HITS(AV, M0, M1, M2, M3, COLBASE) do {                        \
    const unsigned gc0 = (unsigned)__popcll((M0) & gmask);                   \
    const unsigned gc1 = (unsigned)__popcll((M1) & gmask);                   \
    const unsigned gc2 = (unsigned)__popcll((M2) & gmask);                   \
    const unsigned gc3 = (unsigned)__popcll((M3) & gmask);                   \
    for (;;) {                                                               \
        unsigned mxc = c0 + gc0, tq;                                         \
        tq = c1 + gc1; mxc = mxc > tq ? mxc : tq;                            \
        tq = c2 + gc2; mxc = mxc > tq ? mxc : tq;                            \
        tq = c3 + gc3; mxc = mxc > tq ? mxc : tq;                            \
        if (__builtin_expect(!__ballot(mxc > CAP), 1)) break;                \
        for (int r = 0; r < 16; ++r) {   /* rare: compact near-full rows */  \
            const int srcl = (r >> 2) * 16;                                  \
            const int jj = r & 3;                                            \
            unsigned cr;                                                     \
            if (jj == 0)      cr = __builtin_amdgcn_readlane(c0, srcl);      \
            else if (jj == 1) cr = __builtin_amdgcn_readlane(c1, srcl);      \
            else if (jj == 2) cr = __builtin_amdgcn_readlane(c2, srcl);      \
            else              cr = __builtin_amdgcn_readlane(c3, srcl);      \
            if (cr + 16u > CAP) {                                            \
                CompRes res = wave_compact(&buf[wave][r][0], (int)cr, lane); \
                if (g == (r >> 2)) {                                         \
                    if (jj == 0)      { c0 = (unsigned)res.nc;               \
                                        tau0 = fmaxf(tau0, res.tau); }       \
                    else if (jj == 1) { c1 = (unsigned)res.nc;               \
                                        tau1 = fmaxf(tau1, res.tau); }       \
                    else if (jj == 2) { c2 = (unsigned)res.nc;               \
                                        tau2 = fmaxf(tau2, res.tau); }       \
                    else              { c3 = (unsigned)res.nc;               \
                                        tau3 = fmaxf(tau3, res.tau); }       \
                }                                                            \
            }                                                                \
        }                                                                    \
    }                                                                        \
    const unsigned colidx = (unsigned)((COLBASE) + (lane & 15));             \
    if (M0) { if (((M0) >> lane) & 1)                                        \
        buf[wave][g * 4 + 0][c0 + (unsigned)__popcll((M0) & gbelow)] =       \
            make_uint2(__float_as_uint((AV)[0]), colidx); }                  \
    if (M1) { if (((M1) >> lane) & 1)                                        \
        buf[wave][g * 4 + 1][c1 + (unsigned)__popcll((M1) & gbelow)] =       \
            make_uint2(__float_as_uint((AV)[1]), colidx); }                  \
    if (M2) { if (((M2) >> lane) & 1)                                        \
        buf[wave][g * 4 + 2][c2 + (unsigned)__popcll((M2) & gbelow)] =       \
            make_uint2(__float_as_uint((AV)[2]), colidx); }                  \
    if (M3) { if (((M3) >> lane) & 1)                                        \
        buf[wave][g * 4 + 3][c3 + (unsigned)__popcll((M3) & gbelow)] =       \
            make_uint2(__float_as_uint((AV)[3]), colidx); }                  \
    c0 += gc0; c1 += gc1; c2 += gc2; c3 += gc3;                              \
} while (0)

#define RANGE_LOOP(T0, T1, GEC)  do {                                        \
    bf16x8 Bc[4], Bn[4];                                                     \
    _Pragma("unroll")                                                        \
    for (int i = 0; i < 4; ++i) Bc[i] = bp[((T0) + i) * 64];                 \
    for (int t = (T0); t < (T1); t += 4) {                                   \
        _Pragma("unroll")                                                    \
        for (int i = 0; i < 4; ++i) {                                        \
            int tp = t + 4 + i; if (tp >= (T1)) tp = (T1) - 1;               \
            Bn[i] = bp[tp * 64];                                             \
        }                                                                    \
        f32x4 A4[4];                                                         \
        _Pragma("unroll")                                                    \
        for (int i = 0; i < 4; ++i)                                          \
            A4[i] = __builtin_amdgcn_mfma_f32_16x16x32_bf16(afrag, Bc[i],    \
                                                            zacc, 0, 0, 0);  \
        _Pragma("unroll")                                                    \
        for (int i = 0; i < 4; ++i) {                                        \
            const f32x4 av = A4[i];                                          \
            const u64 m0 = __ballot(GEC ? (av[0] >= tau0) : (av[0] > tau0)); \
            const u64 m1 = __ballot(GEC ? (av[1] >= tau1) : (av[1] > tau1)); \
            const u64 m2 = __ballot(GEC ? (av[2] >= tau2) : (av[2] > tau2)); \
            const u64 m3 = __ballot(GEC ? (av[3] >= tau3) : (av[3] > tau3)); \
            if (m0 | m1 | m2 | m3)                                           \
                INSERT_HITS(av, m0, m1, m2, m3, (pblk + t + i) * 16);        \
        }                                                                    \
        _Pragma("unroll")                                                    \
        for (int i = 0; i < 4; ++i) Bc[i] = Bn[i];                           \
    }                                                                        \
} while (0)

    RANGE_LOOP(0, 32, true);       // prepass range re-scan with >= (tie anchors)
    RANGE_LOOP(32, PBLK, false);   // main stream, strict >

#undef RANGE_LOOP
#undef INSERT_HITS

    // ---- per-part finalize: compact guard, sort, park top-16 keys in slots
#pragma unroll 1
    for (int r = 0; r < 16; ++r) {
        const int srcl = (r >> 2) * 16;
        const int jj = r & 3;
        unsigned cru;
        if (jj == 0)      cru = __builtin_amdgcn_readlane(c0, srcl);
        else if (jj == 1) cru = __builtin_amdgcn_readlane(c1, srcl);
        else if (jj == 2) cru = __builtin_amdgcn_readlane(c2, srcl);
        else              cru = __builtin_amdgcn_readlane(c3, srcl);
        int c = (int)cru;
        uint2* br = &buf[wave][r][0];
        if (c > 64) { CompRes res = wave_compact(br, c, lane); c = res.nc; }
        u64 key = 0;                               // sentinel < any real key
        if (lane < c) { const uint2 e = br[lane]; key = mkkey(e.x, e.y); }
        key = wave_sort_u64(key, lane);
        if (lane >= 48)
            *(u64*)&buf[wave][r][lane - 48] = key;  // part top-16, slots 0..15
    }

    // ---- in-block merge: 64 keys per row (4 disjoint parts x 16) ----
    __syncthreads();
#pragma unroll
    for (int rr = 0; rr < 4; ++rr) {
        const int r2 = wave * 4 + rr;
        u64 key = *(const u64*)&buf[lane >> 4][r2][lane & 15];
        key = wave_sort_u64(key, lane);
        if (lane >= 48)
            knn[(rowbase + r2) * K_NBR + (lane - 48)] = (int)keyidx(key);
    }
}

// ---------------- edge-feature MLP: parallel gather + hoisted W2 -----------
// (unchanged from the proven kernel)
__global__ __launch_bounds__(256, 2) void mlp_kernel(
        const float4* __restrict__ x4,
        const int* __restrict__ knn,
        const float4* __restrict__ W2f4,
        const float* __restrict__ W1,
        const float* __restrict__ b1,
        const float* __restrict__ b2,
        float* __restrict__ out) {
    __shared__ __align__(16) float4 w2s[16][64];     // 16 KB, h4-major
    __shared__ __align__(16) float  h1s[4][32][68];  // 34 KB, per-wave
    __shared__ __align__(16) float4 xjs[4][32];      // 2 KB, per-wave gather
    const int lane = threadIdx.x & 63;
    const int wave = threadIdx.x >> 6;
    const int kq   = lane >> 4;
    const int gp   = lane & 15;
    const int p0   = (blockIdx.x * 4 + wave) * 2;    // 2 points per wave

    for (int q = threadIdx.x; q < 1024; q += 256)
        w2s[q & 15][q >> 4] = W2f4[q];               // w2s[h4][g]
    __syncthreads();

    float w1r[8];
#pragma unroll
    for (int c = 0; c < 8; ++c) w1r[c] = W1[lane * 8 + c];
    const float b1r = b1[lane];
    float b2r[4];
#pragma unroll
    for (int gq = 0; gq < 4; ++gq) b2r[gq] = b2[gq * 16 + gp];

    // parallel gather: 32 indices coalesced, 32 x4 loads in flight at once
    if (lane < 32) {
        const int pp = lane >> 4;
        const int nb = knn[(p0 + pp) * K_NBR + (lane & 15)];
        xjs[wave][lane] = x4[nb];
    }
    // wave-private LDS + in-wave vmcnt/lgkmcnt ordering: no barrier

    // layer 1 for both points (lane = hidden feature h)
#pragma unroll
    for (int pp = 0; pp < 2; ++pp) {
        const float4 xi = x4[p0 + pp];
        float hb = b1r;
        hb = fmaf(w1r[4] - w1r[0], xi.x, hb);
        hb = fmaf(w1r[5] - w1r[1], xi.y, hb);
        hb = fmaf(w1r[6] - w1r[2], xi.z, hb);
        hb = fmaf(w1r[7] - w1r[3], xi.w, hb);
#pragma unroll
        for (int k = 0; k < K_NBR; ++k) {
            const float4 xj = xjs[wave][pp * 16 + k];
            float h = hb;
            h = fmaf(w1r[0], xj.x, h);
            h = fmaf(w1r[1], xj.y, h);
            h = fmaf(w1r[2], xj.z, h);
            h = fmaf(w1r[3], xj.w, h);
            h1s[wave][pp * 16 + k][lane] = fmaxf(h, 0.0f);
        }
    }

    // layer 2: acc[pp][kk][gq] (packed pairs over h), h4-outer, w4 hoisted
    v2f acc[2][4][4];
#pragma unroll
    for (int pp = 0; pp < 2; ++pp)
#pragma unroll
        for (int kk = 0; kk < 4; ++kk)
#pragma unroll
            for (int gq = 0; gq < 4; ++gq)
                acc[pp][kk][gq] = (v2f){b2r[gq], 0.0f};

#pragma unroll
    for (int h4 = 0; h4 < 16; ++h4) {
        float4 w4[4];
#pragma unroll
        for (int gq = 0; gq < 4; ++gq) w4[gq] = w2s[h4][gq * 16 + gp];
#pragma unroll
        for (int pp = 0; pp < 2; ++pp) {
#pragma unroll
            for (int kk = 0; kk < 4; ++kk) {
                const float4 hv =
                    *(const float4*)&h1s[wave][pp * 16 + kq * 4 + kk][h4 * 4];
#pragma unroll
                for (int gq = 0; gq < 4; ++gq) {
                    acc[pp][kk][gq] = __builtin_elementwise_fma(
                        (v2f){hv.x, hv.y}, (v2f){w4[gq].x, w4[gq].y},
                        acc[pp][kk][gq]);
                    acc[pp][kk][gq] = __builtin_elementwise_fma(
                        (v2f){hv.z, hv.w}, (v2f){w4[gq].z, w4[gq].w},
                        acc[pp][kk][gq]);
                }
            }
        }
    }

#pragma unroll
    for (int pp = 0; pp < 2; ++pp) {
        float s[4];
#pragma unroll
        for (int gq = 0; gq < 4; ++gq) {
            s[gq] = 0.0f;
#pragma unroll
            for (int kk = 0; kk < 4; ++kk) {
                const float v = acc[pp][kk][gq].x + acc[pp][kk][gq].y;
                s[gq] += fmaxf(v, 0.0f);
            }
        }
#pragma unroll
        for (int off = 16; off <= 32; off <<= 1)
#pragma unroll
            for (int gq = 0; gq < 4; ++gq)
                s[gq] += __shfl_xor(s[gq], off, 64);

        out[(p0 + pp) * H_DIM + kq * 16 + gp] = s[kq] * (1.0f / 16.0f);
    }
}

extern "C" void kernel_launch(void* const* d_in, const int* in_sizes, int n_in,
                              void* d_out, int out_size, void* d_ws, size_t ws_size,
                              hipStream_t stream) {
    (void)in_sizes; (void)n_in; (void)out_size; (void)ws_size;
    const float* x  = (const float*)d_in[0];
    const float* W1 = (const float*)d_in[1];
    const float* b1 = (const float*)d_in[2];
    const float* W2 = (const float*)d_in[3];
    const float* b2 = (const float*)d_in[4];
    float* out = (float*)d_out;

    int* knn   = (int*)d_ws;                                        // 1 MB
    u16* bfrag = (u16*)((char*)d_ws + (size_t)N_PTS * K_NBR * sizeof(int)); // 1 MB

    const float4* x4 = (const float4*)x;

    prep_kernel<<<N_PTS / 256, 256, 0, stream>>>(x4, bfrag);
    knn_kernel <<<N_PTS / 16,  256, 0, stream>>>(x4, bfrag, knn);
    mlp_kernel <<<N_PTS / 8,   256, 0, stream>>>(
        x4, knn, (const float4*)W2, W1, b1, b2, out);
}